// Round 1
// baseline (5524.483 us; speedup 1.0000x reference)
//
#include <hip/hip_runtime.h>

#define FDIM 128

// dst[n][o] = sum_k src[n][k] * W[k][o].  One wave per row; W staged in LDS.
// Safe for src == dst (row n fully read before row n written; no restrict on src/dst).
__global__ __launch_bounds__(256)
void gemm_rows(const float* src, const float* __restrict__ W, float* dst, int nrows) {
    __shared__ float sW[FDIM * FDIM];              // 64 KB
    for (int i = threadIdx.x; i < FDIM * FDIM; i += 256) sW[i] = W[i];
    __syncthreads();
    const int lane = threadIdx.x & 63;
    const int wid  = (blockIdx.x * 256 + threadIdx.x) >> 6;
    const int nw   = (gridDim.x * 256) >> 6;
    for (int n = wid; n < nrows; n += nw) {
        const float* xr = src + (size_t)n * FDIM;
        float acc0 = 0.f, acc1 = 0.f;
        #pragma unroll 8
        for (int k = 0; k < FDIM; ++k) {
            float xv = xr[k];                      // wave-uniform address -> scalar/L1 broadcast
            float2 w = *(const float2*)&sW[k * FDIM + lane * 2];
            acc0 = fmaf(xv, w.x, acc0);
            acc1 = fmaf(xv, w.y, acc1);
        }
        *(float2*)&dst[(size_t)n * FDIM + lane * 2] = make_float2(acc0, acc1);
    }
}

// COO scatter-add: 32 threads per edge, float4 per thread, hardware f32 atomics.
__global__ __launch_bounds__(256)
void spmm_scatter(const int* __restrict__ row, const int* __restrict__ col,
                  const float* __restrict__ vals, const float* __restrict__ y,
                  float* __restrict__ out, int E) {
    long long tid = (long long)blockIdx.x * 256 + threadIdx.x;
    int e = (int)(tid >> 5);
    if (e >= E) return;
    int c = ((int)tid & 31) << 2;                  // feature offset 0,4,...,124
    int r  = row[e];
    int cl = col[e];
    float v = vals[e];
    float4 yv = *(const float4*)&y[(size_t)cl * FDIM + c];
    float* po = out + (size_t)r * FDIM + c;
    unsafeAtomicAdd(po + 0, v * yv.x);
    unsafeAtomicAdd(po + 1, v * yv.y);
    unsafeAtomicAdd(po + 2, v * yv.z);
    unsafeAtomicAdd(po + 3, v * yv.w);
}

extern "C" void kernel_launch(void* const* d_in, const int* in_sizes, int n_in,
                              void* d_out, int out_size, void* d_ws, size_t ws_size,
                              hipStream_t stream) {
    const int*   row  = (const int*)d_in[0];
    const int*   col  = (const int*)d_in[1];
    const float* vals = (const float*)d_in[2];
    const float* x    = (const float*)d_in[3];
    const float* W    = (const float*)d_in[4];
    float* out = (float*)d_out;

    const int E = in_sizes[0];
    const int N = in_sizes[3] / FDIM;
    const size_t ybytes = (size_t)N * FDIM * sizeof(float);

    hipMemsetAsync(d_out, 0, (size_t)out_size * sizeof(float), stream);

    const int scatter_blocks = (E + 7) / 8;        // E*32 threads / 256
    if (ws_size >= ybytes) {
        // Fused: y = x @ W, then scatter y.
        float* y = (float*)d_ws;
        gemm_rows<<<1024, 256, 0, stream>>>(x, W, y, N);
        spmm_scatter<<<scatter_blocks, 256, 0, stream>>>(row, col, vals, y, out, E);
    } else {
        // Fallback: scatter x into out (= z), then in-place row GEMM.
        spmm_scatter<<<scatter_blocks, 256, 0, stream>>>(row, col, vals, x, out, E);
        gemm_rows<<<1024, 256, 0, stream>>>(out, W, out, N);
    }
}

// Round 2
// 969.960 us; speedup vs baseline: 5.6956x; 5.6956x over previous
//
#include <hip/hip_runtime.h>

#define FDIM 128

// dst[n][o] = sum_k src[n][k] * W[k][o].  One wave per row; W staged in LDS.
__global__ __launch_bounds__(256)
void gemm_rows(const float* src, const float* __restrict__ W, float* dst, int nrows) {
    __shared__ float sW[FDIM * FDIM];              // 64 KB
    for (int i = threadIdx.x; i < FDIM * FDIM; i += 256) sW[i] = W[i];
    __syncthreads();
    const int lane = threadIdx.x & 63;
    const int wid  = (blockIdx.x * 256 + threadIdx.x) >> 6;
    const int nw   = (gridDim.x * 256) >> 6;
    for (int n = wid; n < nrows; n += nw) {
        const float* xr = src + (size_t)n * FDIM;
        float acc0 = 0.f, acc1 = 0.f;
        #pragma unroll 8
        for (int k = 0; k < FDIM; ++k) {
            float xv = xr[k];
            float2 w = *(const float2*)&sW[k * FDIM + lane * 2];
            acc0 = fmaf(xv, w.x, acc0);
            acc1 = fmaf(xv, w.y, acc1);
        }
        *(float2*)&dst[(size_t)n * FDIM + lane * 2] = make_float2(acc0, acc1);
    }
}

// --- counting-sort pipeline -------------------------------------------------

__global__ __launch_bounds__(256)
void edge_histogram(const int* __restrict__ row, int* __restrict__ counts, int E) {
    int i = blockIdx.x * 256 + threadIdx.x;
    if (i < E) atomicAdd(&counts[row[i]], 1);
}

// Single-block exclusive scan of counts[0..n) -> offsets/cursor; offsets[n]=total.
__global__ __launch_bounds__(1024)
void scan_counts(const int* __restrict__ counts, int* __restrict__ offsets,
                 int* __restrict__ cursor, int n) {
    __shared__ int lds[1024];
    __shared__ int carry;
    const int tid = threadIdx.x;
    if (tid == 0) carry = 0;
    __syncthreads();
    for (int base = 0; base < n; base += 1024) {
        int i = base + tid;
        int v = (i < n) ? counts[i] : 0;
        lds[tid] = v;
        __syncthreads();
        #pragma unroll
        for (int off = 1; off < 1024; off <<= 1) {
            int t = (tid >= off) ? lds[tid - off] : 0;
            __syncthreads();
            lds[tid] += t;
            __syncthreads();
        }
        int excl = lds[tid] - v + carry;
        if (i < n) { offsets[i] = excl; cursor[i] = excl; }
        __syncthreads();
        if (tid == 0) carry += lds[1023];
        __syncthreads();
    }
    if (threadIdx.x == 0) offsets[n] = carry;
}

// Scatter edges into row-grouped order: skv[pos] = (col, bitcast(val)).
__global__ __launch_bounds__(256)
void edge_scatter(const int* __restrict__ row, const int* __restrict__ col,
                  const float* __restrict__ vals, int* __restrict__ cursor,
                  int2* __restrict__ skv, int E) {
    int i = blockIdx.x * 256 + threadIdx.x;
    if (i >= E) return;
    int pos = atomicAdd(&cursor[row[i]], 1);
    skv[pos] = make_int2(col[i], __float_as_int(vals[i]));
}

// One wave per row: out[r] = sum_e val_e * y[col_e].  No atomics.
__global__ __launch_bounds__(256)
void spmm_csr(const int* __restrict__ offsets, const int2* __restrict__ skv,
              const float* __restrict__ y, float* __restrict__ out, int N) {
    const int wid  = (blockIdx.x * 256 + threadIdx.x) >> 6;
    const int lane = threadIdx.x & 63;
    if (wid >= N) return;
    const int s = offsets[wid], t = offsets[wid + 1];
    float acc0 = 0.f, acc1 = 0.f;
    int2 kv = (s < t) ? skv[s] : make_int2(0, 0);
    for (int e = s; e < t; ++e) {
        int2 cur = kv;
        if (e + 1 < t) kv = skv[e + 1];          // prefetch next edge
        float v = __int_as_float(cur.y);
        float2 yv = *(const float2*)&y[(size_t)cur.x * FDIM + lane * 2];
        acc0 = fmaf(v, yv.x, acc0);
        acc1 = fmaf(v, yv.y, acc1);
    }
    *(float2*)&out[(size_t)wid * FDIM + lane * 2] = make_float2(acc0, acc1);
}

// --- fallback (round-1 atomic scatter) --------------------------------------

__global__ __launch_bounds__(256)
void spmm_scatter(const int* __restrict__ row, const int* __restrict__ col,
                  const float* __restrict__ vals, const float* __restrict__ y,
                  float* __restrict__ out, int E) {
    long long tid = (long long)blockIdx.x * 256 + threadIdx.x;
    int e = (int)(tid >> 5);
    if (e >= E) return;
    int c = ((int)tid & 31) << 2;
    int r  = row[e];
    int cl = col[e];
    float v = vals[e];
    float4 yv = *(const float4*)&y[(size_t)cl * FDIM + c];
    float* po = out + (size_t)r * FDIM + c;
    unsafeAtomicAdd(po + 0, v * yv.x);
    unsafeAtomicAdd(po + 1, v * yv.y);
    unsafeAtomicAdd(po + 2, v * yv.z);
    unsafeAtomicAdd(po + 3, v * yv.w);
}

extern "C" void kernel_launch(void* const* d_in, const int* in_sizes, int n_in,
                              void* d_out, int out_size, void* d_ws, size_t ws_size,
                              hipStream_t stream) {
    const int*   row  = (const int*)d_in[0];
    const int*   col  = (const int*)d_in[1];
    const float* vals = (const float*)d_in[2];
    const float* x    = (const float*)d_in[3];
    const float* W    = (const float*)d_in[4];
    float* out = (float*)d_out;

    const int E = in_sizes[0];
    const int N = in_sizes[3] / FDIM;
    const size_t ybytes = (size_t)N * FDIM * sizeof(float);

    // workspace layout
    char* p = (char*)d_ws;
    float* y       = (float*)p;  p += ybytes;
    int*   counts  = (int*)p;    p += (size_t)N * 4;
    int*   offsets = (int*)p;    p += (size_t)(N + 1) * 4;
    int*   cursor  = (int*)p;    p += (size_t)N * 4;
    int2*  skv     = (int2*)p;   p += (size_t)E * 8;
    const size_t need_fast = (size_t)(p - (char*)d_ws);

    const int eb = (E + 255) / 256;

    if (ws_size >= need_fast) {
        gemm_rows<<<1024, 256, 0, stream>>>(x, W, y, N);
        hipMemsetAsync(counts, 0, (size_t)N * 4, stream);
        edge_histogram<<<eb, 256, 0, stream>>>(row, counts, E);
        scan_counts<<<1, 1024, 0, stream>>>(counts, offsets, cursor, N);
        edge_scatter<<<eb, 256, 0, stream>>>(row, col, vals, cursor, skv, E);
        spmm_csr<<<(N * 64 + 255) / 256, 256, 0, stream>>>(offsets, skv, y, out, N);
    } else if (ws_size >= ybytes) {
        float* yw = (float*)d_ws;
        hipMemsetAsync(d_out, 0, (size_t)out_size * sizeof(float), stream);
        gemm_rows<<<1024, 256, 0, stream>>>(x, W, yw, N);
        spmm_scatter<<<(E + 7) / 8, 256, 0, stream>>>(row, col, vals, yw, out, E);
    } else {
        hipMemsetAsync(d_out, 0, (size_t)out_size * sizeof(float), stream);
        spmm_scatter<<<(E + 7) / 8, 256, 0, stream>>>(row, col, vals, x, out, E);
        gemm_rows<<<1024, 256, 0, stream>>>(out, W, out, N);
    }
}

// Round 4
// 735.224 us; speedup vs baseline: 7.5140x; 1.3193x over previous
//
#include <hip/hip_runtime.h>
#include <hip/hip_bf16.h>

#define FDIM 128

typedef __attribute__((ext_vector_type(8))) short short8v;   // 8 bf16 in 4 VGPRs
typedef __attribute__((ext_vector_type(4))) float f32x4;

__device__ __forceinline__ short f2bf(float f) {             // RNE f32 -> bf16 bits
    unsigned u = __float_as_uint(f);
    u += 0x7FFFu + ((u >> 16) & 1u);
    return (short)(u >> 16);
}

// ---- y = x @ W via MFMA bf16.  Wave: 16 rows x 64 cols; block: 32 rows x 128 cols.
__global__ __launch_bounds__(256)
void gemm_mfma(const float* __restrict__ x, const float* __restrict__ W,
               unsigned short* __restrict__ y, int nrows) {
    const int lane = threadIdx.x & 63;
    const int wid  = threadIdx.x >> 6;         // 0..3
    const int colHalf = wid & 1;               // cols 0-63 / 64-127
    const int rowSub  = wid >> 1;              // row sub-tile 0/1
    const int l15 = lane & 15;
    const int lhi = lane >> 4;

    // Preload B fragments (W): elem j -> k = ks*32 + lhi*8 + j, col = colHalf*64 + ct*16 + l15
    short8v bfrag[4][4];
    #pragma unroll
    for (int ks = 0; ks < 4; ++ks)
      #pragma unroll
      for (int ct = 0; ct < 4; ++ct) {
        const int col = colHalf * 64 + ct * 16 + l15;
        const int kb  = ks * 32 + lhi * 8;
        short8v f;
        #pragma unroll
        for (int j = 0; j < 8; ++j) f[j] = f2bf(W[(kb + j) * FDIM + col]);
        bfrag[ks][ct] = f;
      }

    const int nTiles = (nrows + 31) >> 5;
    for (int tile = blockIdx.x; tile < nTiles; tile += gridDim.x) {
        const int rowBase = tile * 32 + rowSub * 16;
        int arow = rowBase + l15;
        if (arow >= nrows) arow = nrows - 1;   // clamp: duplicate reads, stores guarded
        const float* xr = x + (size_t)arow * FDIM;
        f32x4 acc[4] = {};
        #pragma unroll
        for (int ks = 0; ks < 4; ++ks) {
            const int kb = ks * 32 + lhi * 8;
            float4 xa = *(const float4*)&xr[kb];
            float4 xb = *(const float4*)&xr[kb + 4];
            short8v af;
            af[0] = f2bf(xa.x); af[1] = f2bf(xa.y); af[2] = f2bf(xa.z); af[3] = f2bf(xa.w);
            af[4] = f2bf(xb.x); af[5] = f2bf(xb.y); af[6] = f2bf(xb.z); af[7] = f2bf(xb.w);
            #pragma unroll
            for (int ct = 0; ct < 4; ++ct)
                acc[ct] = __builtin_amdgcn_mfma_f32_16x16x32_bf16(af, bfrag[ks][ct], acc[ct], 0, 0, 0);
        }
        // D: row = rowBase + lhi*4 + r, col = colHalf*64 + ct*16 + l15
        #pragma unroll
        for (int ct = 0; ct < 4; ++ct) {
            const int col = colHalf * 64 + ct * 16 + l15;
            #pragma unroll
            for (int r = 0; r < 4; ++r) {
                int orow = rowBase + lhi * 4 + r;
                if (orow < nrows) y[(size_t)orow * FDIM + col] = (unsigned short)f2bf(acc[ct][r]);
            }
        }
    }
}

// ---- counting-sort pipeline (round-2 proven-stable versions) ---------------

__global__ __launch_bounds__(256)
void edge_histogram(const int* __restrict__ row, int* __restrict__ counts, int E) {
    int i = blockIdx.x * 256 + threadIdx.x;
    if (i < E) atomicAdd(&counts[row[i]], 1);
}

// Single-block exclusive scan of counts[0..n) -> offsets/cursor; offsets[n]=total.
__global__ __launch_bounds__(1024)
void scan_counts(const int* __restrict__ counts, int* __restrict__ offsets,
                 int* __restrict__ cursor, int n) {
    __shared__ int lds[1024];
    __shared__ int carry;
    const int tid = threadIdx.x;
    if (tid == 0) carry = 0;
    __syncthreads();
    for (int base = 0; base < n; base += 1024) {
        int i = base + tid;
        int v = (i < n) ? counts[i] : 0;
        lds[tid] = v;
        __syncthreads();
        #pragma unroll
        for (int off = 1; off < 1024; off <<= 1) {
            int t = (tid >= off) ? lds[tid - off] : 0;
            __syncthreads();
            lds[tid] += t;
            __syncthreads();
        }
        int excl = lds[tid] - v + carry;
        if (i < n) { offsets[i] = excl; cursor[i] = excl; }
        __syncthreads();
        if (tid == 0) carry += lds[1023];
        __syncthreads();
    }
    if (threadIdx.x == 0) offsets[n] = carry;
}

// Scatter edges into row-grouped order: skv[pos] = (col, bitcast(val)).
__global__ __launch_bounds__(256)
void edge_scatter(const int* __restrict__ row, const int* __restrict__ col,
                  const float* __restrict__ vals, int* __restrict__ cursor,
                  int2* __restrict__ skv, int E) {
    int i = blockIdx.x * 256 + threadIdx.x;
    if (i >= E) return;
    int pos = atomicAdd(&cursor[row[i]], 1);
    skv[pos] = make_int2(col[i], __float_as_int(vals[i]));
}

// ---- one wave per row, y in bf16, 2 edges in flight ------------------------
__global__ __launch_bounds__(256)
void spmm_csr_bf16(const int* __restrict__ offsets, const int2* __restrict__ skv,
                   const unsigned* __restrict__ yu, float* __restrict__ out, int N) {
    const int wid  = (blockIdx.x * 256 + threadIdx.x) >> 6;
    const int lane = threadIdx.x & 63;
    if (wid >= N) return;
    const int s = offsets[wid], t = offsets[wid + 1];
    float a0 = 0.f, a1 = 0.f, b0 = 0.f, b1 = 0.f;
    int e = s;
    for (; e + 2 <= t; e += 2) {
        int2 k0 = skv[e], k1 = skv[e + 1];
        unsigned u0 = yu[(size_t)k0.x * 64 + lane];
        unsigned u1 = yu[(size_t)k1.x * 64 + lane];
        float v0 = __int_as_float(k0.y), v1 = __int_as_float(k1.y);
        a0 = fmaf(v0, __uint_as_float(u0 << 16), a0);
        a1 = fmaf(v0, __uint_as_float(u0 & 0xffff0000u), a1);
        b0 = fmaf(v1, __uint_as_float(u1 << 16), b0);
        b1 = fmaf(v1, __uint_as_float(u1 & 0xffff0000u), b1);
    }
    if (e < t) {
        int2 k0 = skv[e];
        unsigned u0 = yu[(size_t)k0.x * 64 + lane];
        float v0 = __int_as_float(k0.y);
        a0 = fmaf(v0, __uint_as_float(u0 << 16), a0);
        a1 = fmaf(v0, __uint_as_float(u0 & 0xffff0000u), a1);
    }
    *(float2*)&out[(size_t)wid * FDIM + lane * 2] = make_float2(a0 + b0, a1 + b1);
}

// ---- fallbacks (round-1 path, never taken when ws is large enough) ---------

__global__ __launch_bounds__(256)
void gemm_rows(const float* src, const float* __restrict__ W, float* dst, int nrows) {
    __shared__ float sW[FDIM * FDIM];
    for (int i = threadIdx.x; i < FDIM * FDIM; i += 256) sW[i] = W[i];
    __syncthreads();
    const int lane = threadIdx.x & 63;
    const int wid  = (blockIdx.x * 256 + threadIdx.x) >> 6;
    const int nw   = (gridDim.x * 256) >> 6;
    for (int n = wid; n < nrows; n += nw) {
        const float* xr = src + (size_t)n * FDIM;
        float acc0 = 0.f, acc1 = 0.f;
        #pragma unroll 8
        for (int k = 0; k < FDIM; ++k) {
            float xv = xr[k];
            float2 w = *(const float2*)&sW[k * FDIM + lane * 2];
            acc0 = fmaf(xv, w.x, acc0);
            acc1 = fmaf(xv, w.y, acc1);
        }
        *(float2*)&dst[(size_t)n * FDIM + lane * 2] = make_float2(acc0, acc1);
    }
}

__global__ __launch_bounds__(256)
void spmm_scatter(const int* __restrict__ row, const int* __restrict__ col,
                  const float* __restrict__ vals, const float* __restrict__ y,
                  float* __restrict__ out, int E) {
    long long tid = (long long)blockIdx.x * 256 + threadIdx.x;
    int e = (int)(tid >> 5);
    if (e >= E) return;
    int c = ((int)tid & 31) << 2;
    int r  = row[e];
    int cl = col[e];
    float v = vals[e];
    float4 yv = *(const float4*)&y[(size_t)cl * FDIM + c];
    float* po = out + (size_t)r * FDIM + c;
    unsafeAtomicAdd(po + 0, v * yv.x);
    unsafeAtomicAdd(po + 1, v * yv.y);
    unsafeAtomicAdd(po + 2, v * yv.z);
    unsafeAtomicAdd(po + 3, v * yv.w);
}

extern "C" void kernel_launch(void* const* d_in, const int* in_sizes, int n_in,
                              void* d_out, int out_size, void* d_ws, size_t ws_size,
                              hipStream_t stream) {
    const int*   row  = (const int*)d_in[0];
    const int*   col  = (const int*)d_in[1];
    const float* vals = (const float*)d_in[2];
    const float* x    = (const float*)d_in[3];
    const float* W    = (const float*)d_in[4];
    float* out = (float*)d_out;

    const int E = in_sizes[0];
    const int N = in_sizes[3] / FDIM;

    // workspace layout (fast path)
    char* p = (char*)d_ws;
    unsigned short* yb = (unsigned short*)p;  p += (size_t)N * FDIM * 2;   // y bf16
    int*   counts   = (int*)p;   p += (size_t)N * 4;
    int*   offsets  = (int*)p;   p += (size_t)(N + 1) * 4 + 12;            // keep 16B align
    int*   cursor   = (int*)p;   p += (size_t)N * 4;
    int2*  skv      = (int2*)p;  p += (size_t)E * 8;
    const size_t need_fast = (size_t)(p - (char*)d_ws);

    const int eb = (E + 255) / 256;

    if (ws_size >= need_fast) {
        hipMemsetAsync(counts, 0, (size_t)N * 4, stream);
        gemm_mfma<<<512, 256, 0, stream>>>(x, W, yb, N);
        edge_histogram<<<eb, 256, 0, stream>>>(row, counts, E);
        scan_counts<<<1, 1024, 0, stream>>>(counts, offsets, cursor, N);
        edge_scatter<<<eb, 256, 0, stream>>>(row, col, vals, cursor, skv, E);
        spmm_csr_bf16<<<((size_t)N * 64 + 255) / 256, 256, 0, stream>>>(offsets, skv, (const unsigned*)yb, out, N);
    } else if (ws_size >= (size_t)N * FDIM * 4) {
        float* yw = (float*)d_ws;
        hipMemsetAsync(d_out, 0, (size_t)out_size * sizeof(float), stream);
        gemm_rows<<<1024, 256, 0, stream>>>(x, W, yw, N);
        spmm_scatter<<<(E + 7) / 8, 256, 0, stream>>>(row, col, vals, yw, out, E);
    } else {
        hipMemsetAsync(d_out, 0, (size_t)out_size * sizeof(float), stream);
        spmm_scatter<<<(E + 7) / 8, 256, 0, stream>>>(row, col, vals, x, out, E);
        gemm_rows<<<1024, 256, 0, stream>>>(out, W, out, N);
    }
}

// Round 5
// 640.262 us; speedup vs baseline: 8.6285x; 1.1483x over previous
//
#include <hip/hip_runtime.h>
#include <hip/hip_bf16.h>

#define FDIM 128

typedef __attribute__((ext_vector_type(8))) short short8v;   // 8 bf16 in 4 VGPRs
typedef __attribute__((ext_vector_type(4))) float f32x4;

__device__ __forceinline__ short f2bf(float f) {             // RNE f32 -> bf16 bits
    unsigned u = __float_as_uint(f);
    u += 0x7FFFu + ((u >> 16) & 1u);
    return (short)(u >> 16);
}

// ---- y = x @ W via MFMA bf16.  Wave: 16 rows x 64 cols; block: 32 rows x 128 cols.
__global__ __launch_bounds__(256)
void gemm_mfma(const float* __restrict__ x, const float* __restrict__ W,
               unsigned short* __restrict__ y, int nrows) {
    const int lane = threadIdx.x & 63;
    const int wid  = threadIdx.x >> 6;         // 0..3
    const int colHalf = wid & 1;               // cols 0-63 / 64-127
    const int rowSub  = wid >> 1;              // row sub-tile 0/1
    const int l15 = lane & 15;
    const int lhi = lane >> 4;

    // Preload B fragments (W): elem j -> k = ks*32 + lhi*8 + j, col = colHalf*64 + ct*16 + l15
    short8v bfrag[4][4];
    #pragma unroll
    for (int ks = 0; ks < 4; ++ks)
      #pragma unroll
      for (int ct = 0; ct < 4; ++ct) {
        const int col = colHalf * 64 + ct * 16 + l15;
        const int kb  = ks * 32 + lhi * 8;
        short8v f;
        #pragma unroll
        for (int j = 0; j < 8; ++j) f[j] = f2bf(W[(kb + j) * FDIM + col]);
        bfrag[ks][ct] = f;
      }

    const int nTiles = (nrows + 31) >> 5;
    for (int tile = blockIdx.x; tile < nTiles; tile += gridDim.x) {
        const int rowBase = tile * 32 + rowSub * 16;
        int arow = rowBase + l15;
        if (arow >= nrows) arow = nrows - 1;   // clamp: duplicate reads, stores guarded
        const float* xr = x + (size_t)arow * FDIM;
        f32x4 acc[4] = {};
        #pragma unroll
        for (int ks = 0; ks < 4; ++ks) {
            const int kb = ks * 32 + lhi * 8;
            float4 xa = *(const float4*)&xr[kb];
            float4 xb = *(const float4*)&xr[kb + 4];
            short8v af;
            af[0] = f2bf(xa.x); af[1] = f2bf(xa.y); af[2] = f2bf(xa.z); af[3] = f2bf(xa.w);
            af[4] = f2bf(xb.x); af[5] = f2bf(xb.y); af[6] = f2bf(xb.z); af[7] = f2bf(xb.w);
            #pragma unroll
            for (int ct = 0; ct < 4; ++ct)
                acc[ct] = __builtin_amdgcn_mfma_f32_16x16x32_bf16(af, bfrag[ks][ct], acc[ct], 0, 0, 0);
        }
        // D: row = rowBase + lhi*4 + r, col = colHalf*64 + ct*16 + l15
        #pragma unroll
        for (int ct = 0; ct < 4; ++ct) {
            const int col = colHalf * 64 + ct * 16 + l15;
            #pragma unroll
            for (int r = 0; r < 4; ++r) {
                int orow = rowBase + lhi * 4 + r;
                if (orow < nrows) y[(size_t)orow * FDIM + col] = (unsigned short)f2bf(acc[ct][r]);
            }
        }
    }
}

// ---- counting-sort pipeline ------------------------------------------------

__global__ __launch_bounds__(256)
void edge_histogram(const int* __restrict__ row, int* __restrict__ counts, int E) {
    int i = blockIdx.x * 256 + threadIdx.x;
    if (i < E) atomicAdd(&counts[row[i]], 1);
}

// Single-block exclusive scan of counts[0..n) -> offsets/cursor; offsets[n]=total.
__global__ __launch_bounds__(1024)
void scan_counts(const int* __restrict__ counts, int* __restrict__ offsets,
                 int* __restrict__ cursor, int n) {
    __shared__ int lds[1024];
    __shared__ int carry;
    const int tid = threadIdx.x;
    if (tid == 0) carry = 0;
    __syncthreads();
    for (int base = 0; base < n; base += 1024) {
        int i = base + tid;
        int v = (i < n) ? counts[i] : 0;
        lds[tid] = v;
        __syncthreads();
        #pragma unroll
        for (int off = 1; off < 1024; off <<= 1) {
            int t = (tid >= off) ? lds[tid - off] : 0;
            __syncthreads();
            lds[tid] += t;
            __syncthreads();
        }
        int excl = lds[tid] - v + carry;
        if (i < n) { offsets[i] = excl; cursor[i] = excl; }
        __syncthreads();
        if (tid == 0) carry += lds[1023];
        __syncthreads();
    }
    if (threadIdx.x == 0) offsets[n] = carry;
}

// Chunked XCD-affine scatter: chunk = row / rowsPerChunk; blocks with
// blockIdx%8 == chunk process only that chunk's rows, so each ~3.2MB skv
// window is written from (mostly) one XCD's L2 -> full-line evictions.
__global__ __launch_bounds__(256)
void edge_scatter_chunked(const int* __restrict__ row, const int* __restrict__ col,
                          const float* __restrict__ vals, int* __restrict__ cursor,
                          int2* __restrict__ skv, int E, int rowsPerChunk) {
    const int chunk = blockIdx.x & 7;
    const int sub   = blockIdx.x >> 3;
    const int nsub  = gridDim.x >> 3;
    const int lo = chunk * rowsPerChunk;
    const int hi = lo + rowsPerChunk;
    for (int i = sub * 256 + threadIdx.x; i < E; i += nsub * 256) {
        int r = row[i];
        if (r >= lo && r < hi) {
            int pos = atomicAdd(&cursor[r], 1);
            skv[pos] = make_int2(col[i], __float_as_int(vals[i]));
        }
    }
}

// ---- one wave per row, y in bf16, 2 edges in flight ------------------------
__global__ __launch_bounds__(256)
void spmm_csr_bf16(const int* __restrict__ offsets, const int2* __restrict__ skv,
                   const unsigned* __restrict__ yu, float* __restrict__ out, int N) {
    const int wid  = (blockIdx.x * 256 + threadIdx.x) >> 6;
    const int lane = threadIdx.x & 63;
    if (wid >= N) return;
    const int s = offsets[wid], t = offsets[wid + 1];
    float a0 = 0.f, a1 = 0.f, b0 = 0.f, b1 = 0.f;
    int e = s;
    for (; e + 2 <= t; e += 2) {
        int2 k0 = skv[e], k1 = skv[e + 1];
        unsigned u0 = yu[(size_t)k0.x * 64 + lane];
        unsigned u1 = yu[(size_t)k1.x * 64 + lane];
        float v0 = __int_as_float(k0.y), v1 = __int_as_float(k1.y);
        a0 = fmaf(v0, __uint_as_float(u0 << 16), a0);
        a1 = fmaf(v0, __uint_as_float(u0 & 0xffff0000u), a1);
        b0 = fmaf(v1, __uint_as_float(u1 << 16), b0);
        b1 = fmaf(v1, __uint_as_float(u1 & 0xffff0000u), b1);
    }
    if (e < t) {
        int2 k0 = skv[e];
        unsigned u0 = yu[(size_t)k0.x * 64 + lane];
        float v0 = __int_as_float(k0.y);
        a0 = fmaf(v0, __uint_as_float(u0 << 16), a0);
        a1 = fmaf(v0, __uint_as_float(u0 & 0xffff0000u), a1);
    }
    *(float2*)&out[(size_t)wid * FDIM + lane * 2] = make_float2(a0 + b0, a1 + b1);
}

// ---- fallbacks (round-1 path, never taken when ws is large enough) ---------

__global__ __launch_bounds__(256)
void gemm_rows(const float* src, const float* __restrict__ W, float* dst, int nrows) {
    __shared__ float sW[FDIM * FDIM];
    for (int i = threadIdx.x; i < FDIM * FDIM; i += 256) sW[i] = W[i];
    __syncthreads();
    const int lane = threadIdx.x & 63;
    const int wid  = (blockIdx.x * 256 + threadIdx.x) >> 6;
    const int nw   = (gridDim.x * 256) >> 6;
    for (int n = wid; n < nrows; n += nw) {
        const float* xr = src + (size_t)n * FDIM;
        float acc0 = 0.f, acc1 = 0.f;
        #pragma unroll 8
        for (int k = 0; k < FDIM; ++k) {
            float xv = xr[k];
            float2 w = *(const float2*)&sW[k * FDIM + lane * 2];
            acc0 = fmaf(xv, w.x, acc0);
            acc1 = fmaf(xv, w.y, acc1);
        }
        *(float2*)&dst[(size_t)n * FDIM + lane * 2] = make_float2(acc0, acc1);
    }
}

__global__ __launch_bounds__(256)
void spmm_scatter(const int* __restrict__ row, const int* __restrict__ col,
                  const float* __restrict__ vals, const float* __restrict__ y,
                  float* __restrict__ out, int E) {
    long long tid = (long long)blockIdx.x * 256 + threadIdx.x;
    int e = (int)(tid >> 5);
    if (e >= E) return;
    int c = ((int)tid & 31) << 2;
    int r  = row[e];
    int cl = col[e];
    float v = vals[e];
    float4 yv = *(const float4*)&y[(size_t)cl * FDIM + c];
    float* po = out + (size_t)r * FDIM + c;
    unsafeAtomicAdd(po + 0, v * yv.x);
    unsafeAtomicAdd(po + 1, v * yv.y);
    unsafeAtomicAdd(po + 2, v * yv.z);
    unsafeAtomicAdd(po + 3, v * yv.w);
}

extern "C" void kernel_launch(void* const* d_in, const int* in_sizes, int n_in,
                              void* d_out, int out_size, void* d_ws, size_t ws_size,
                              hipStream_t stream) {
    const int*   row  = (const int*)d_in[0];
    const int*   col  = (const int*)d_in[1];
    const float* vals = (const float*)d_in[2];
    const float* x    = (const float*)d_in[3];
    const float* W    = (const float*)d_in[4];
    float* out = (float*)d_out;

    const int E = in_sizes[0];
    const int N = in_sizes[3] / FDIM;

    // workspace layout (fast path)
    char* p = (char*)d_ws;
    unsigned short* yb = (unsigned short*)p;  p += (size_t)N * FDIM * 2;   // y bf16
    int*   counts   = (int*)p;   p += (size_t)N * 4;
    int*   offsets  = (int*)p;   p += (size_t)(N + 1) * 4 + 12;            // keep 16B align
    int*   cursor   = (int*)p;   p += (size_t)N * 4;
    int2*  skv      = (int2*)p;  p += (size_t)E * 8;
    const size_t need_fast = (size_t)(p - (char*)d_ws);

    const int eb = (E + 255) / 256;
    const int rowsPerChunk = (N + 7) / 8;

    if (ws_size >= need_fast) {
        hipMemsetAsync(counts, 0, (size_t)N * 4, stream);
        gemm_mfma<<<512, 256, 0, stream>>>(x, W, yb, N);
        edge_histogram<<<eb, 256, 0, stream>>>(row, counts, E);
        scan_counts<<<1, 1024, 0, stream>>>(counts, offsets, cursor, N);
        edge_scatter_chunked<<<2048, 256, 0, stream>>>(row, col, vals, cursor, skv, E, rowsPerChunk);
        spmm_csr_bf16<<<((size_t)N * 64 + 255) / 256, 256, 0, stream>>>(offsets, skv, (const unsigned*)yb, out, N);
    } else if (ws_size >= (size_t)N * FDIM * 4) {
        float* yw = (float*)d_ws;
        hipMemsetAsync(d_out, 0, (size_t)out_size * sizeof(float), stream);
        gemm_rows<<<1024, 256, 0, stream>>>(x, W, yw, N);
        spmm_scatter<<<(E + 7) / 8, 256, 0, stream>>>(row, col, vals, yw, out, E);
    } else {
        hipMemsetAsync(d_out, 0, (size_t)out_size * sizeof(float), stream);
        spmm_scatter<<<(E + 7) / 8, 256, 0, stream>>>(row, col, vals, x, out, E);
        gemm_rows<<<1024, 256, 0, stream>>>(out, W, out, N);
    }
}